// Round 16
// baseline (126.015 us; speedup 1.0000x reference)
//
#include <hip/hip_runtime.h>
#include <math.h>

// SE(3)-Transformer block, MI355X. B=4, N=192, CS=16, CV=4, DIM=28, NB=10.
// Round 15 candidate, resubmitted (round-15 bench failed on GPU acquisition).
// SINGLE fused kernel, T workspace eliminated. Rationale: rounds 7/12/14
// proved precomp ~30-47us regardless of staging; cause is the inter-kernel
// L2 flush (non-coherent XCD L2s) forcing T's 8MB write + 26MB read through
// cold HBM. Fusion kills the round-trip:
//  k-side: per-block tables A/B/D/E = qd_i contracted into W2k (5.3KB LDS)
//          -> score is ~100 LDS-FMA per (pair,h), no k-chunks.
//  v-side: W2v staged in LDS [16][404] (pad keeps 16B align, 2-way banks),
//          v-chunk computed on the fly into acc[28], no cc[80].
// Hk/Hv inline from emb_sh. All r7 measured-good scaffolding kept.

#define NN 192
#define MAXM 192
#define WVS 404   // padded row stride (floats) for W2v in LDS

constexpr float C1   = 0.17677669529663687f;  // 1/(4*sqrt(2))
constexpr float C2   = 0.17677669529663687f;
constexpr float C3   = 0.35355339059327373f;  // 1/(2*sqrt(2))
constexpr float C4   = 0.20412414523193154f;  // 1/sqrt(24)
constexpr float CS1f = 0.17677669529663687f;
constexpr float CS2f = 0.20412414523193154f;
constexpr float RS10 = 0.31622776601683794f;
constexpr float GAIN4 = 1.679f * 0.25f;
constexpr float SQRT3 = 1.7320508075688772f;
constexpr float CEMB = (float)(1.14136 * 7.3890560989306495 * 3.1622776601683795);

__global__ __launch_bounds__(256) void se3_fused(
  const float* __restrict__ f, const float* __restrict__ pos,
  const float* __restrict__ wq_s, const float* __restrict__ wq_v,
  const float* __restrict__ w1k, const float* __restrict__ w2k,
  const float* __restrict__ w1v, const float* __restrict__ w2v,
  const float* __restrict__ dws, const float* __restrict__ dwv,
  float* __restrict__ out)
{
  const int bi = blockIdx.x;
  const int b = bi / NN, i = bi - b*NN;
  const int tid = threadIdx.x;
  const int lane = tid & 63, wid = tid >> 6;

  __shared__ float Wv[16*WVS];        // 25.9 KB  W2v rows, padded
  __shared__ float A_t[16][17];       // qd_s . W1k   (pad 17)
  __shared__ float B_t[16][4];        // qd_s . W4k
  __shared__ float D_t[16][49];       // qd_v . W2k   [c*3+x]
  __shared__ float E_t[16][13];       // qd_v . W3k   [c*3+x], c<4
  __shared__ float qd_sh[28];
  __shared__ float qs_sh[16], qv_sh[12];
  __shared__ float fi_sh[28];
  __shared__ float w1_sh[320];        // k(160) | v(160), *RS10
  __shared__ int   s_node[MAXM];
  __shared__ float s_cut[MAXM], s_dist[MAXM];
  __shared__ float s_shx[MAXM], s_shy[MAXM], s_shz[MAXM];
  __shared__ float emb_sh[MAXM*10];
  __shared__ float le_sh[MAXM], att_sh[MAXM];
  __shared__ int   cnt_sh, vsh;
  __shared__ float red_sh[4];
  __shared__ float opart[4][28];

  // ---- stage: f_i, w1, W2v; init flags
  if (tid < 28) fi_sh[tid] = f[bi*28 + tid];
  if (tid == 0) { cnt_sh = 0; vsh = 0; }
  if (tid < 160) { w1_sh[tid] = w1k[tid]*RS10; w1_sh[160+tid] = w1v[tid]*RS10; }
  for (int t = tid; t < 6400; t += 256) Wv[(t/400)*WVS + (t%400)] = w2v[t];
  __syncthreads();

  // ---- qd_i (two tiny stages) + valid_i
  if (tid < 28 && fi_sh[tid] != 0.f) vsh = 1;     // benign same-value race
  if (tid < 16) {
    float a = 0.f;
    #pragma unroll
    for (int c = 0; c < 16; ++c) a = fmaf(fi_sh[c], wq_s[c*16 + tid], a);
    qs_sh[tid] = a * 0.25f;
  } else if (tid < 28) {
    const int idx = tid - 16, o = idx / 3, x = idx - o*3;
    float a = 0.f;
    #pragma unroll
    for (int c = 0; c < 4; ++c) a = fmaf(fi_sh[16 + c*3 + x], wq_v[c*4 + o], a);
    qv_sh[idx] = a * 0.5f;
  }
  __syncthreads();
  if (tid < 16) {
    float a = 0.f;
    #pragma unroll
    for (int c = 0; c < 16; ++c) a = fmaf(qs_sh[c], dws[c*16 + tid], a);
    qd_sh[tid] = a * CS1f;
  } else if (tid < 28) {
    const int idx = tid - 16, d2 = idx / 3, x = idx - d2*3;
    float a = 0.f;
    #pragma unroll
    for (int c = 0; c < 4; ++c) a = fmaf(qv_sh[c*3 + x], dwv[c*4 + d2], a);
    qd_sh[tid] = a * CS2f;
  }
  __syncthreads();
  const int vali = vsh;

  // ---- build k-score tables from W2k (global, L2-hot) : thread = (h,c)
  {
    const int h = tid >> 4, c = tid & 15;
    const float* Wr = w2k + h*400;
    float a = 0.f;
    #pragma unroll
    for (int o = 0; o < 16; ++o) a = fmaf(qd_sh[o], Wr[c*16 + o], a);
    A_t[h][c] = C1 * a;
    #pragma unroll
    for (int x = 0; x < 3; ++x) {
      float d = 0.f;
      #pragma unroll
      for (int o = 0; o < 4; ++o) d = fmaf(qd_sh[16 + o*3 + x], Wr[256 + c*4 + o], d);
      D_t[h][c*3 + x] = C2 * d;
    }
    if (c < 4) {
      float bs = 0.f;
      #pragma unroll
      for (int o = 0; o < 16; ++o) bs = fmaf(qd_sh[o], Wr[336 + c*16 + o], bs);
      B_t[h][c] = C4 * bs;
      #pragma unroll
      for (int x = 0; x < 3; ++x) {
        float e = 0.f;
        #pragma unroll
        for (int o = 0; o < 4; ++o) e = fmaf(qd_sh[16 + o*3 + x], Wr[320 + c*4 + o], e);
        E_t[h][c*3 + x] = C3 * e;
      }
    }
  }

  // ---- compaction (valid_j computed inline from f_j)
  {
    const float pix = pos[bi*3+0], piy = pos[bi*3+1], piz = pos[bi*3+2];
    if (tid < NN) {
      const int nj = b*NN + tid;
      const float dx = pos[nj*3+0]-pix, dy = pos[nj*3+1]-piy, dz = pos[nj*3+2]-piz;
      const float dist = sqrtf(fmaf(dx,dx,fmaf(dy,dy,dz*dz)) + 1e-12f);
      if (tid != i && dist < 1.5f && vali) {
        bool vj = false;
        const float4* fj4 = (const float4*)(f + nj*28);   // 28 floats, 16B-aligned
        #pragma unroll
        for (int q = 0; q < 7; ++q) {
          const float4 v = fj4[q];
          vj = vj || (v.x != 0.f) || (v.y != 0.f) || (v.z != 0.f) || (v.w != 0.f);
        }
        if (vj) {
          const float cut = expf(-1.f / (10.f * (1.f - dist * (1.f/1.5f))));
          if (cut > 0.f) {
            const int s = atomicAdd(&cnt_sh, 1);
            const float sc = SQRT3 / dist;
            s_node[s] = nj; s_cut[s] = cut; s_dist[s] = dist;
            s_shx[s] = dx*sc; s_shy[s] = dy*sc; s_shz[s] = dz*sc;
          }
        }
      }
    }
  }
  __syncthreads();
  const int M = cnt_sh;
  const int MK = M * 16;

  // ---- radial basis per (pair, k)
  for (int idx = tid; idx < M*10; idx += 256) {
    const int pr = idx / 10, k = idx - pr*10;
    const float dd = (s_dist[pr] - (float)(k+1)*(1.5f/11.f)) * (11.f/1.5f);
    float e = 0.f;
    if (dd > -1.f && dd < 1.f) e = CEMB * expf(-1.f/(1.f+dd) - 1.f/(1.f-dd));
    emb_sh[idx] = e;
  }
  __syncthreads();

  // ---- k-pass: score via tables (no chunks)
  for (int idx = tid; idx < MK; idx += 256) {
    const int pr = idx >> 4, h = idx & 15;
    const int node = s_node[pr];
    const float sx = s_shx[pr], sy = s_shy[pr], sz = s_shz[pr];
    const float* e = emb_sh + pr*10;
    float sk = 0.f;
    #pragma unroll
    for (int q = 0; q < 10; ++q) sk = fmaf(e[q], w1_sh[q*16 + h], sk);
    const float Hk = GAIN4 * sk / (1.f + expf(-sk));

    float fj[28];
    {
      const float4* fj4 = (const float4*)(f + node*28);
      #pragma unroll
      for (int q = 0; q < 7; ++q) ((float4*)fj)[q] = fj4[q];
    }
    float s = 0.f;
    #pragma unroll
    for (int c = 0; c < 16; ++c) {
      const float t = A_t[h][c] + fmaf(sx, D_t[h][c*3], fmaf(sy, D_t[h][c*3+1], sz*D_t[h][c*3+2]));
      s = fmaf(fj[c], t, s);
    }
    #pragma unroll
    for (int c = 0; c < 4; ++c) {
      const float g = fmaf(sx, fj[16+c*3], fmaf(sy, fj[17+c*3], sz*fj[18+c*3]));
      s = fmaf(g, B_t[h][c], s);
      s = fmaf(fj[16+c*3], E_t[h][c*3+0], s);
      s = fmaf(fj[17+c*3], E_t[h][c*3+1], s);
      s = fmaf(fj[18+c*3], E_t[h][c*3+2], s);
    }
    s *= Hk;
    #pragma unroll
    for (int d = 1; d < 16; d <<= 1) s += __shfl_xor(s, d);
    if ((tid & 15) == 0) le_sh[pr] = s;
  }
  __syncthreads();

  // ---- z + att
  float les = 0.f;
  if (tid < M) les = s_cut[tid] * le_sh[tid];
  float z = les;
  #pragma unroll
  for (int d = 1; d < 64; d <<= 1) z += __shfl_xor(z, d);
  if (lane == 0) red_sh[wid] = z;
  __syncthreads();
  z = red_sh[0] + red_sh[1] + red_sh[2] + red_sh[3];
  if (z == 0.f) z = 1.f;
  if (tid < M) {
    const float alpha = les / z;
    att_sh[tid] = alpha > 0.f ? sqrtf(alpha) : 0.f;
  }
  __syncthreads();

  // ---- v-pass: on-the-fly chunks from LDS W2v
  float acc[28];
  #pragma unroll
  for (int c = 0; c < 28; ++c) acc[c] = 0.f;
  for (int idx = tid; idx < MK; idx += 256) {
    const int pr = idx >> 4, h = idx & 15;
    const int node = s_node[pr];
    const float sx = s_shx[pr], sy = s_shy[pr], sz = s_shz[pr];
    const float* e = emb_sh + pr*10;
    float sv = 0.f;
    #pragma unroll
    for (int q = 0; q < 10; ++q) sv = fmaf(e[q], w1_sh[160 + q*16 + h], sv);
    const float Hv = GAIN4 * sv / (1.f + expf(-sv));
    const float a = Hv * att_sh[pr];

    float fj[28];
    {
      const float4* fj4 = (const float4*)(f + node*28);
      #pragma unroll
      for (int q = 0; q < 7; ++q) ((float4*)fj)[q] = fj4[q];
    }
    const float* Wr = Wv + h*WVS;

    // T1: acc[0..15] += a*C1*sum_c fs[c]*W1v[c,o]
    const float aC1 = a * C1;
    #pragma unroll
    for (int c = 0; c < 16; ++c) {
      const float m = aC1 * fj[c];
      const float4* w = (const float4*)(Wr + c*16);
      const float4 w0 = w[0], w1 = w[1], w2 = w[2], w3 = w[3];
      acc[0]  = fmaf(m, w0.x, acc[0]);  acc[1]  = fmaf(m, w0.y, acc[1]);
      acc[2]  = fmaf(m, w0.z, acc[2]);  acc[3]  = fmaf(m, w0.w, acc[3]);
      acc[4]  = fmaf(m, w1.x, acc[4]);  acc[5]  = fmaf(m, w1.y, acc[5]);
      acc[6]  = fmaf(m, w1.z, acc[6]);  acc[7]  = fmaf(m, w1.w, acc[7]);
      acc[8]  = fmaf(m, w2.x, acc[8]);  acc[9]  = fmaf(m, w2.y, acc[9]);
      acc[10] = fmaf(m, w2.z, acc[10]); acc[11] = fmaf(m, w2.w, acc[11]);
      acc[12] = fmaf(m, w3.x, acc[12]); acc[13] = fmaf(m, w3.y, acc[13]);
      acc[14] = fmaf(m, w3.z, acc[14]); acc[15] = fmaf(m, w3.w, acc[15]);
    }
    // T4: acc[0..15] += a*C4*sum_c g[c]*W4v[c,o]
    const float aC4 = a * C4;
    #pragma unroll
    for (int c = 0; c < 4; ++c) {
      const float g = fmaf(sx, fj[16+c*3], fmaf(sy, fj[17+c*3], sz*fj[18+c*3]));
      const float m = aC4 * g;
      const float4* w = (const float4*)(Wr + 336 + c*16);
      const float4 w0 = w[0], w1 = w[1], w2 = w[2], w3 = w[3];
      acc[0]  = fmaf(m, w0.x, acc[0]);  acc[1]  = fmaf(m, w0.y, acc[1]);
      acc[2]  = fmaf(m, w0.z, acc[2]);  acc[3]  = fmaf(m, w0.w, acc[3]);
      acc[4]  = fmaf(m, w1.x, acc[4]);  acc[5]  = fmaf(m, w1.y, acc[5]);
      acc[6]  = fmaf(m, w1.z, acc[6]);  acc[7]  = fmaf(m, w1.w, acc[7]);
      acc[8]  = fmaf(m, w2.x, acc[8]);  acc[9]  = fmaf(m, w2.y, acc[9]);
      acc[10] = fmaf(m, w2.z, acc[10]); acc[11] = fmaf(m, w2.w, acc[11]);
      acc[12] = fmaf(m, w3.x, acc[12]); acc[13] = fmaf(m, w3.y, acc[13]);
      acc[14] = fmaf(m, w3.z, acc[14]); acc[15] = fmaf(m, w3.w, acc[15]);
    }
    // T2: t[o] = sum_c fs[c]*W2v[c,o]; acc_v[o,x] += a*C2*sh_x*t[o]
    float t0 = 0.f, t1 = 0.f, t2 = 0.f, t3 = 0.f;
    #pragma unroll
    for (int c = 0; c < 16; ++c) {
      const float4 w = *(const float4*)(Wr + 256 + c*4);
      t0 = fmaf(fj[c], w.x, t0); t1 = fmaf(fj[c], w.y, t1);
      t2 = fmaf(fj[c], w.z, t2); t3 = fmaf(fj[c], w.w, t3);
    }
    const float aC2 = a * C2;
    {
      const float u0 = aC2*t0, u1 = aC2*t1, u2 = aC2*t2, u3 = aC2*t3;
      acc[16] = fmaf(sx, u0, acc[16]); acc[17] = fmaf(sy, u0, acc[17]); acc[18] = fmaf(sz, u0, acc[18]);
      acc[19] = fmaf(sx, u1, acc[19]); acc[20] = fmaf(sy, u1, acc[20]); acc[21] = fmaf(sz, u1, acc[21]);
      acc[22] = fmaf(sx, u2, acc[22]); acc[23] = fmaf(sy, u2, acc[23]); acc[24] = fmaf(sz, u2, acc[24]);
      acc[25] = fmaf(sx, u3, acc[25]); acc[26] = fmaf(sy, u3, acc[26]); acc[27] = fmaf(sz, u3, acc[27]);
    }
    // T3: acc_v[o,x] += a*C3*sum_c fv[c,x]*W3v[c,o]
    const float aC3 = a * C3;
    #pragma unroll
    for (int c = 0; c < 4; ++c) {
      const float4 w = *(const float4*)(Wr + 320 + c*4);
      const float vx = aC3*fj[16+c*3], vy = aC3*fj[17+c*3], vz = aC3*fj[18+c*3];
      acc[16] = fmaf(vx, w.x, acc[16]); acc[17] = fmaf(vy, w.x, acc[17]); acc[18] = fmaf(vz, w.x, acc[18]);
      acc[19] = fmaf(vx, w.y, acc[19]); acc[20] = fmaf(vy, w.y, acc[20]); acc[21] = fmaf(vz, w.y, acc[21]);
      acc[22] = fmaf(vx, w.z, acc[22]); acc[23] = fmaf(vy, w.z, acc[23]); acc[24] = fmaf(vz, w.z, acc[24]);
      acc[25] = fmaf(vx, w.w, acc[25]); acc[26] = fmaf(vy, w.w, acc[26]); acc[27] = fmaf(vz, w.w, acc[27]);
    }
  }

  // ---- block-wide 28-element reduction
  #pragma unroll
  for (int c = 0; c < 28; ++c) {
    float w = acc[c];
    #pragma unroll
    for (int d = 1; d < 64; d <<= 1) w += __shfl_xor(w, d);
    if (lane == 0) opart[wid][c] = w;
  }
  __syncthreads();
  if (tid < 28) out[bi*28 + tid] = opart[0][tid] + opart[1][tid] + opart[2][tid] + opart[3][tid];
}

extern "C" void kernel_launch(void* const* d_in, const int* in_sizes, int n_in,
                              void* d_out, int out_size, void* d_ws, size_t ws_size,
                              hipStream_t stream) {
  const float* f      = (const float*)d_in[0];
  const float* pos    = (const float*)d_in[1];
  const float* wq_s   = (const float*)d_in[2];
  const float* wq_v   = (const float*)d_in[3];
  const float* fck_w1 = (const float*)d_in[4];
  const float* fck_w2 = (const float*)d_in[5];
  const float* fcv_w1 = (const float*)d_in[6];
  const float* fcv_w2 = (const float*)d_in[7];
  const float* dot_ws = (const float*)d_in[8];
  const float* dot_wv = (const float*)d_in[9];
  float* outp = (float*)d_out;

  const int BN = in_sizes[0] / 28;   // 768 nodes (B*N)

  se3_fused<<<BN, 256, 0, stream>>>(f, pos, wq_s, wq_v,
                                    fck_w1, fck_w2, fcv_w1, fcv_w2,
                                    dot_ws, dot_wv, outp);
}